// Round 4
// baseline (2017.000 us; speedup 1.0000x reference)
//
#include <hip/hip_runtime.h>
#include <hip/hip_fp16.h>

// BiLSTM-CRF forward, MI355X. Round 7: k_lstm v7 — MFMA batched recurrence.
// 16 WGs = 2 dir x 4 batch-groups(16) x 2 col-halves. Per WG per step:
//   h[16,256] @ Wh[256,512] via mfma_f32_16x16x32_f16 (256 MFMA/step),
//   B-frags register-resident (32 uint4/thread, literal-indexed, pinned),
//   h in LDS pre-arranged in A-frag order (producer writes fragment dwords
//   directly -> all reads are wave-contiguous ds_read_b128, conflict-free),
//   gates via transposed [col][batch] LDS, xg staged per-step (coalesced,
//   double-buffered, issue-early/write-late).
// Cross-half h exchange: u64 {tag=s+1, f16-pair} agent-scope atomics via LLC
// (proven protocol from v5/v6), 2 words polled per thread by all 8 waves,
// overlapped under phase-A MFMAs. f16 numerics identical to fdot2 path.

typedef unsigned int  uint32;
typedef unsigned short ushort16;
typedef unsigned long long uint64;
typedef __attribute__((ext_vector_type(8))) short  short8;   // 8 bf16 (4 VGPRs) — MFMA A/B frag
typedef __attribute__((ext_vector_type(8))) _Float16 half8;  // 8 f16 (4 VGPRs) — MFMA A/B frag
typedef __attribute__((ext_vector_type(4))) float  floatx4;  // MFMA C/D frag

#define BB 64
#define TT 512
#define NT (BB*TT)        // 32768 rows
#define G4 1024           // 4*H
#define NL 9
#define GSTR 18           // gT row stride (dwords): 2-way max on read/write
#define XSTR 522          // xl row stride (ushorts): odd-dword m-stride on read

__device__ inline float bf2f(ushort16 u) {
  return __builtin_bit_cast(float, ((uint32)u) << 16);
}
__device__ inline ushort16 f2bf(float f) {  // RN-even bf16
  uint32 u = __builtin_bit_cast(uint32, f);
  u += 0x7fffu + ((u >> 16) & 1u);
  return (ushort16)(u >> 16);
}
__device__ inline float sigf(float x)  { return 1.0f / (1.0f + __expf(-x)); }
__device__ inline float tanhf_(float x){ return 1.0f - 2.0f / (1.0f + __expf(2.0f * x)); }
__device__ inline uint32 f16pk(float lo, float hi) {
  const uint32 a = (uint32)__builtin_bit_cast(ushort16, (_Float16)lo);
  const uint32 b = (uint32)__builtin_bit_cast(ushort16, (_Float16)hi);
  return a | (b << 16);
}

// ---------------- K1: seq_len ----------------
__global__ __launch_bounds__(64) void k_seqlen(const int* __restrict__ tokens,
                                               int* __restrict__ slen,
                                               float* __restrict__ out_sl) {
  const int b = blockIdx.x, lane = threadIdx.x;
  int cnt = 0;
  for (int t = lane; t < TT; t += 64) cnt += (tokens[b * TT + t] != 0) ? 1 : 0;
  #pragma unroll
  for (int off = 32; off >= 1; off >>= 1) cnt += __shfl_down(cnt, off, 64);
  if (lane == 0) { slen[b] = cnt; out_sl[b] = (float)cnt; }
}

// ---------------- K2a: embedding gather -> bf16 A matrix [NT][256] ----------------
__global__ __launch_bounds__(256) void k_embed(const int* __restrict__ tokens,
                                               const float* __restrict__ emb,
                                               ushort16* __restrict__ A) {
  const int f = blockIdx.x * 256 + threadIdx.x;  // float4 group, NT*256/4 total
  const int e = f * 4;
  const int row = e >> 8;
  const int col = e & 255;
  const int tok = tokens[row];
  const float4 v = *(const float4*)(emb + (size_t)tok * 256 + col);
  uint32 lo = (uint32)f2bf(v.x) | ((uint32)f2bf(v.y) << 16);
  uint32 hi = (uint32)f2bf(v.z) | ((uint32)f2bf(v.w) << 16);
  *(uint2*)(A + e) = make_uint2(lo, hi);
}

// ---------------- K2b: BT[c][k] = Wx_{f|b}[k][c] bf16, c in [0,2048) ----------------
__global__ __launch_bounds__(256) void k_wxprep(const float* __restrict__ Wxf,
                                                const float* __restrict__ Wxb,
                                                ushort16* __restrict__ BT) {
  const int id = blockIdx.x * 256 + threadIdx.x;   // 2048*256
  const int c = id >> 8, k = id & 255;
  const float v = (c < G4) ? Wxf[k * G4 + c] : Wxb[k * G4 + (c - G4)];
  BT[c * 256 + k] = f2bf(v);
}

// ---------------- K2c: Wh -> half2 pack, layout [k2][1024] ----------------
__global__ __launch_bounds__(256) void k_whprep(const float* __restrict__ Wh,
                                                uint32* __restrict__ W2) {
  const int id = blockIdx.x * 256 + threadIdx.x;   // 128*1024
  const int k2 = id >> 10, c = id & 1023;
  const float w0 = Wh[(2 * k2) * G4 + c];
  const float w1 = Wh[(2 * k2 + 1) * G4 + c];
  const ushort16 b0 = __builtin_bit_cast(ushort16, (_Float16)w0);
  const ushort16 b1 = __builtin_bit_cast(ushort16, (_Float16)w1);
  W2[id] = ((uint32)b1 << 16) | (uint32)b0;
}

// ---------------- K3: xg GEMM  [NT,256] @ [256,2048] -> bf16 xg_f | xg_b ----------------
__global__ __launch_bounds__(256) void k_gemm_xg(const ushort16* __restrict__ A,
                                                 const ushort16* __restrict__ BT,
                                                 const float* __restrict__ bias_f,
                                                 const float* __restrict__ bias_b,
                                                 ushort16* __restrict__ xgf,
                                                 ushort16* __restrict__ xgb) {
  __shared__ __align__(16) ushort16 As[64 * 36];
  __shared__ __align__(16) ushort16 Bs[64 * 36];
  const int m0 = blockIdx.x * 64;
  const int n0 = blockIdx.y * 64;
  const int tid = threadIdx.x;
  const int wave = tid >> 6, lane = tid & 63;
  const int lr = tid >> 2;            // staging row 0..63
  const int lc = (tid & 3) * 8;       // staging col {0,8,16,24}
  const int am = lane & 15, aq = lane >> 4;
  floatx4 acc[4];
  #pragma unroll
  for (int j = 0; j < 4; ++j) acc[j] = (floatx4){0.f, 0.f, 0.f, 0.f};

  for (int k0 = 0; k0 < 256; k0 += 32) {
    const uint4 va = *(const uint4*)(A  + ((m0 + lr) * 256 + k0 + lc));
    const uint4 vb = *(const uint4*)(BT + ((n0 + lr) * 256 + k0 + lc));
    *(uint2*)&As[lr * 36 + lc]     = make_uint2(va.x, va.y);
    *(uint2*)&As[lr * 36 + lc + 4] = make_uint2(va.z, va.w);
    *(uint2*)&Bs[lr * 36 + lc]     = make_uint2(vb.x, vb.y);
    *(uint2*)&Bs[lr * 36 + lc + 4] = make_uint2(vb.z, vb.w);
    __syncthreads();
    union { uint2 u[2]; short8 s; } fa, fb;
    fa.u[0] = *(const uint2*)&As[(wave * 16 + am) * 36 + aq * 8];
    fa.u[1] = *(const uint2*)&As[(wave * 16 + am) * 36 + aq * 8 + 4];
    #pragma unroll
    for (int j = 0; j < 4; ++j) {
      fb.u[0] = *(const uint2*)&Bs[(j * 16 + am) * 36 + aq * 8];
      fb.u[1] = *(const uint2*)&Bs[(j * 16 + am) * 36 + aq * 8 + 4];
      acc[j] = __builtin_amdgcn_mfma_f32_16x16x32_bf16(fa.s, fb.s, acc[j], 0, 0, 0);
    }
    __syncthreads();
  }
  // C/D layout (m89/m91-verified): col = lane&15, row = (lane>>4)*4 + reg
  const int orow = m0 + wave * 16 + aq * 4;
  #pragma unroll
  for (int j = 0; j < 4; ++j) {
    const int col = n0 + j * 16 + am;
    const float bv = (col < G4) ? bias_f[col] : bias_b[col - G4];
    #pragma unroll
    for (int r = 0; r < 4; ++r) {
      const float v = acc[j][r] + bv;
      const int row = orow + r;
      if (col < G4) xgf[row * G4 + col] = f2bf(v);
      else          xgb[row * G4 + (col - G4)] = f2bf(v);
    }
  }
}

// ---------------- K3b: zero the h-exchange tag buffer (per launch/replay) ----------------
__global__ __launch_bounds__(256) void k_zero(uint64* __restrict__ xh) {
  xh[blockIdx.x * 256 + threadIdx.x] = 0ull;
}

// ---------------- K4: LSTM recurrence v7 — MFMA, 16 batches/WG ----------------
// bid: dir=bid>>3, grp=(bid>>1)&3 (batches grp*16..+15), half=bid&1; peer=bid^1.
// Wave w: gate q=w>>1, cols u_w=(w&1)*64+j*16+(lane&15), j=0..3 (half-local
// units 0..127). B-frag wq[j*8+kk]: W2 rows permuted own-half-first.
// haf[par][2048]: A-frag-ordered h pairs; dword(kk,l,d)=kk*256+l*4+d holds
// pair p=kk*16+(l>>4)*4+d of batch m=l&15; kk 0..3 own, 4..7 peer.
// Nonlin thread t owns batch m=(t>>1)&15, units u0=(t>>5)*8+(t&1)*4 (4 units
// = own haf dwords 2t,2t+1) -> writes its fragment dwords directly.
__global__ __launch_bounds__(512, 2) void k_lstm(const ushort16* __restrict__ xgf,
                                                 const ushort16* __restrict__ xgb,
                                                 const uint32* __restrict__ Whf,
                                                 const uint32* __restrict__ Whb,
                                                 uint64* __restrict__ xh,
                                                 float* __restrict__ enc) {
  __shared__ __align__(16) uint32 haf[2][2048];       // 16 KB  A-frag h pairs
  __shared__ __align__(16) float  gT[512 * GSTR];     // 36 KB  gates [col][batch]
  __shared__ __align__(16) ushort16 xl[2][16 * XSTR]; // 33 KB  xg slice [b][col]
  const int bid  = blockIdx.x;
  const int dir  = bid >> 3;
  const int grp  = (bid >> 1) & 3;
  const int half = bid & 1;
  const int tid  = threadIdx.x;
  const int w = tid >> 6, l = tid & 63;
  const int n = l & 15, aq = l >> 4;
  const ushort16* __restrict__ xg = dir ? xgb : xgf;
  const uint32* __restrict__ W2   = dir ? Whb : Whf;
  uint64* const xmine = xh + ((size_t)bid << 11);          // [2 par][16 m][64 p]
  const uint64* const xpeer = xh + ((size_t)(bid ^ 1) << 11);

  // ---- B fragments: register-resident, literal-indexed, pinned ----
  const int qg = w >> 1;
  const int gcolbase = qg * 256 + half * 128 + (w & 1) * 64 + n;
  uint4 wq[32];
  #pragma unroll
  for (int j = 0; j < 4; ++j) {
    const int gcol = gcolbase + j * 16;
    #pragma unroll
    for (int kk = 0; kk < 8; ++kk) {
      const int kb = (kk < 4) ? (half * 64 + kk * 16)
                              : ((1 - half) * 64 + (kk - 4) * 16);
      union { uint32 u[4]; uint4 v; } t_;
      #pragma unroll
      for (int d = 0; d < 4; ++d)
        t_.u[d] = W2[(size_t)(kb + aq * 4 + d) * 1024 + gcol];
      wq[j * 8 + kk] = t_.v;
    }
  }
  #pragma unroll
  for (int i = 0; i < 32; ++i)
    asm volatile("" : "+v"(wq[i].x), "+v"(wq[i].y), "+v"(wq[i].z), "+v"(wq[i].w));

  // ---- per-role index precompute ----
  const int m_nl = (tid >> 1) & 15;                 // nonlin: batch
  const int u0   = (tid >> 5) * 8 + (tid & 1) * 4;  // nonlin: first unit (of 4)
  const int p0   = u0 >> 1;                         // nonlin: first pair
  const int m_pl = tid & 15;                        // poll: batch
  const int pp0  = (tid >> 4) * 2;                  // poll: first peer pair
  const int haf_pl = ((4 + (pp0 >> 4)) * 64 + ((pp0 >> 2) & 3) * 16 + m_pl) * 4
                   + (pp0 & 3);                     // poll: haf dword (d even)
  const int srow = tid >> 5;                        // stage: batch row
  const int slc  = (tid & 31) * 16;                 // stage: local col base
  const size_t sgoff = (size_t)((slc >> 7) * 256 + half * 128 + (slc & 127));
  const int batch0 = grp * 16;

  float c0 = 0.f, c1 = 0.f, c2 = 0.f, c3 = 0.f;     // cell state (4 units)

  // ---- prologue: h0 = 0, stage xl[0] ----
  *(uint4*)&haf[0][tid * 4] = make_uint4(0u, 0u, 0u, 0u);
  {
    const int ts = dir ? (TT - 1) : 0;
    const ushort16* src = xg + ((size_t)((batch0 + srow) * TT + ts)) * G4 + sgoff;
    const uint4 x0 = *(const uint4*)src;
    const uint4 x1 = *(const uint4*)(src + 8);
    uint32* dst = (uint32*)&xl[0][srow * XSTR + slc];
    dst[0] = x0.x; dst[1] = x0.y; dst[2] = x0.z; dst[3] = x0.w;
    dst[4] = x1.x; dst[5] = x1.y; dst[6] = x1.z; dst[7] = x1.w;
  }
  __syncthreads();

  for (int s = 0; s < TT; ++s) {
    const int par = s & 1;
    // issue next-step xg loads early (write late — T14)
    uint4 x0, x1;
    const bool do_stage = (s + 1 < TT);
    if (do_stage) {
      const int ts1 = dir ? (TT - 2 - s) : (s + 1);
      const ushort16* src = xg + ((size_t)((batch0 + srow) * TT + ts1)) * G4 + sgoff;
      x0 = *(const uint4*)src;
      x1 = *(const uint4*)(src + 8);
    }
    // ---- phase A: own-half k (kk 0..3) ----
    floatx4 a0 = {0.f,0.f,0.f,0.f}, a1 = {0.f,0.f,0.f,0.f};
    floatx4 a2 = {0.f,0.f,0.f,0.f}, a3 = {0.f,0.f,0.f,0.f};
    const uint32* hafp = haf[par];
    #pragma unroll
    for (int kk = 0; kk < 4; ++kk) {
      const half8 av = *(const half8*)(hafp + kk * 256 + l * 4); // contiguous b128
      a0 = __builtin_amdgcn_mfma_f32_16x16x32_f16(av, __builtin_bit_cast(half8, wq[ 0 + kk]), a0, 0, 0, 0);
      a1 = __builtin_amdgcn_mfma_f32_16x16x32_f16(av, __builtin_bit_cast(half8, wq[ 8 + kk]), a1, 0, 0, 0);
      a2 = __builtin_amdgcn_mfma_f32_16x16x32_f16(av, __builtin_bit_cast(half8, wq[16 + kk]), a2, 0, 0, 0);
      a3 = __builtin_amdgcn_mfma_f32_16x16x32_f16(av, __builtin_bit_cast(half8, wq[24 + kk]), a3, 0, 0, 0);
    }
    // ---- poll peer h-half (all 8 waves, 2 words each; overlaps phase A) ----
    if (s > 0) {
      const uint64* src = xpeer + (size_t)par * 1024 + m_pl * 64 + pp0;
      const uint32 want = (uint32)s;
      uint64 v0, v1;
      for (;;) {
        v0 = __hip_atomic_load(src,     __ATOMIC_RELAXED, __HIP_MEMORY_SCOPE_AGENT);
        v1 = __hip_atomic_load(src + 1, __ATOMIC_RELAXED, __HIP_MEMORY_SCOPE_AGENT);
        if (__all(((uint32)(v0 >> 32) == want) && ((uint32)(v1 >> 32) == want))) break;
        __builtin_amdgcn_s_sleep(1);
      }
      *(uint2*)&haf[par][haf_pl] = make_uint2((uint32)v0, (uint32)v1);
    }
    // write next-step xg slice
    if (do_stage) {
      uint32* dst = (uint32*)&xl[par ^ 1][srow * XSTR + slc];
      dst[0] = x0.x; dst[1] = x0.y; dst[2] = x0.z; dst[3] = x0.w;
      dst[4] = x1.x; dst[5] = x1.y; dst[6] = x1.z; dst[7] = x1.w;
    }
    __syncthreads();
    // ---- phase B: peer-half k (kk 4..7) ----
    #pragma unroll
    for (int kk = 4; kk < 8; ++kk) {
      const half8 av = *(const half8*)(hafp + kk * 256 + l * 4);
      a0 = __builtin_amdgcn_mfma_f32_16x16x32_f16(av, __builtin_bit_cast(half8, wq[ 0 + kk]), a0, 0, 0, 0);
      a1 = __builtin_amdgcn_mfma_f32_16x16x32_f16(av, __builtin_bit_cast(half8, wq[ 8 + kk]), a1, 0, 0, 0);
      a2 = __builtin_amdgcn_mfma_f32_16x16x32_f16(av, __builtin_bit_cast(half8, wq[16 + kk]), a2, 0, 0, 0);
      a3 = __builtin_amdgcn_mfma_f32_16x16x32_f16(av, __builtin_bit_cast(half8, wq[24 + kk]), a3, 0, 0, 0);
    }
    // ---- gates -> gT[col][batch] (C layout: col=lane&15, row=aq*4+reg) ----
    {
      const int cb = (qg * 128 + (w & 1) * 64 + n) * GSTR + aq * 4;
      *(float2*)&gT[cb +  0 * GSTR] = make_float2(a0[0], a0[1]);
      *(float2*)&gT[cb +  0 * GSTR + 2] = make_float2(a0[2], a0[3]);
      *(float2*)&gT[cb + 16 * GSTR] = make_float2(a1[0], a1[1]);
      *(float2*)&gT[cb + 16 * GSTR + 2] = make_float2(a1[2], a1[3]);
      *(float2*)&gT[cb + 32 * GSTR] = make_float2(a2[0], a2[1]);
      *(float2*)&gT[cb + 32 * GSTR + 2] = make_float2(a2[2], a2[3]);
      *(float2*)&gT[cb + 48 * GSTR] = make_float2(a3[0], a3[1]);
      *(float2*)&gT[cb + 48 * GSTR + 2] = make_float2(a3[2], a3[3]);
    }
    __syncthreads();
    // ---- nonlinearity: 4 units x 1 batch per thread ----
    {
      const int ts = dir ? (TT - 1 - s) : s;
      const ushort16* xr = &xl[par][m_nl * XSTR];
      float h[4];
      #pragma unroll
      for (int j = 0; j < 4; ++j) {
        const int u = u0 + j;
        const float pi = gT[(0 * 128 + u) * GSTR + m_nl] + bf2f(xr[0 * 128 + u]);
        const float pf = gT[(1 * 128 + u) * GSTR + m_nl] + bf2f(xr[1 * 128 + u]);
        const float pg = gT[(2 * 128 + u) * GSTR + m_nl] + bf2f(xr[2 * 128 + u]);
        const float po = gT[(3 * 128 + u) * GSTR + m_nl] + bf2f(xr[3 * 128 + u]);
        float& c = (j == 0) ? c0 : (j == 1) ? c1 : (j == 2) ? c2 : c3;
        c = sigf(pf) * c + sigf(pi) * tanhf_(pg);
        h[j] = sigf(po) * tanhf_(c);
      }
      *(float4*)&enc[((size_t)((batch0 + m_nl) * TT + ts)) * 512
                     + dir * 256 + half * 128 + u0] = *(float4*)h;
      const uint32 pk0 = f16pk(h[0], h[1]);
      const uint32 pk1 = f16pk(h[2], h[3]);
      *(uint2*)&haf[par ^ 1][tid * 2] = make_uint2(pk0, pk1);  // own A-frag dwords
      if (s + 1 < TT) {
        const uint64 tagv = ((uint64)(uint32)(s + 1)) << 32;
        uint64* dst = xmine + (size_t)(par ^ 1) * 1024 + m_nl * 64 + p0;
        __hip_atomic_store(dst,     tagv | (uint64)pk0,
                           __ATOMIC_RELAXED, __HIP_MEMORY_SCOPE_AGENT);
        __hip_atomic_store(dst + 1, tagv | (uint64)pk1,
                           __ATOMIC_RELAXED, __HIP_MEMORY_SCOPE_AGENT);
      }
    }
    __syncthreads();
  }
}

// ---------------- K5: logits = enc @ W_dense + b ----------------
__global__ __launch_bounds__(256) void k_dense(const float* __restrict__ enc,
                                               const float* __restrict__ Wd,
                                               const float* __restrict__ bd,
                                               float* __restrict__ logits) {
  __shared__ float Wl[512 * NL];
  __shared__ float bl[NL];
  const int tid = threadIdx.x;
  for (int i = tid; i < 512 * NL; i += 256) Wl[i] = Wd[i];
  if (tid < NL) bl[tid] = bd[tid];
  __syncthreads();
  const int wave = tid >> 6, lane = tid & 63;
  const int row = blockIdx.x * 4 + wave;
  const float* er = enc + (size_t)row * 512;
  float p[NL];
  #pragma unroll
  for (int c = 0; c < NL; ++c) p[c] = 0.f;
  #pragma unroll
  for (int u = 0; u < 8; ++u) {
    const int k = u * 64 + lane;
    const float v = er[k];
    const float* wr = &Wl[k * NL];
    #pragma unroll
    for (int c = 0; c < NL; ++c) p[c] += v * wr[c];
  }
  #pragma unroll
  for (int c = 0; c < NL; ++c) {
    #pragma unroll
    for (int off = 32; off >= 1; off >>= 1) p[c] += __shfl_down(p[c], off, 64);
  }
  if (lane == 0) {
    float* orow = logits + (size_t)row * NL;
    #pragma unroll
    for (int c = 0; c < NL; ++c) orow[c] = p[c] + bl[c];
  }
}

// ---------------- K6: CRF log-likelihood ----------------
__global__ __launch_bounds__(64) void k_crf(const float* __restrict__ logits,
                                            const int* __restrict__ labels,
                                            const int* __restrict__ slen,
                                            const float* __restrict__ trans,
                                            float* __restrict__ out_ll) {
  __shared__ float tr[NL * NL];
  __shared__ float alpha[NL];
  const int b = blockIdx.x;
  const int lane = threadIdx.x;
  for (int i = lane; i < NL * NL; i += 64) tr[i] = trans[i];
  __syncthreads();
  const int len = slen[b];
  const int* tg = labels + b * TT;
  const float* lg = logits + (size_t)b * TT * NL;
  float s = 0.f;
  for (int t = lane; t < TT; t += 64)
    if (t < len) s += lg[t * NL + tg[t]];
  for (int t = lane; t < TT - 1; t += 64)
    if (t + 1 < len) s += tr[tg[t] * NL + tg[t + 1]];
  #pragma unroll
  for (int off = 32; off >= 1; off >>= 1) s += __shfl_down(s, off, 64);
  if (lane < NL) alpha[lane] = lg[lane];
  __syncthreads();
  if (lane < NL) {
    const int j = lane;
    for (int t = 1; t < TT; ++t) {
      if (t < len) {
        float av[NL];
        float m = -1e30f;
        #pragma unroll
        for (int i = 0; i < NL; ++i) { av[i] = alpha[i] + tr[i * NL + j]; m = fmaxf(m, av[i]); }
        float ss = 0.f;
        #pragma unroll
        for (int i = 0; i < NL; ++i) ss += __expf(av[i] - m);
        const float nj = m + __logf(ss) + lg[t * NL + j];
        alpha[j] = nj;
      }
    }
  }
  __syncthreads();
  if (lane == 0) {
    float m = -1e30f;
    #pragma unroll
    for (int i = 0; i < NL; ++i) m = fmaxf(m, alpha[i]);
    float ss = 0.f;
    #pragma unroll
    for (int i = 0; i < NL; ++i) ss += __expf(alpha[i] - m);
    out_ll[b] = s - (m + __logf(ss));
  }
}

extern "C" void kernel_launch(void* const* d_in, const int* in_sizes, int n_in,
                              void* d_out, int out_size, void* d_ws, size_t ws_size,
                              hipStream_t stream) {
  (void)in_sizes; (void)n_in; (void)out_size; (void)ws_size;
  const int*   tokens = (const int*)d_in[0];
  const int*   labels = (const int*)d_in[1];
  const float* emb    = (const float*)d_in[2];
  const float* Wxf    = (const float*)d_in[3];
  const float* Whf    = (const float*)d_in[4];
  const float* bf_    = (const float*)d_in[5];
  const float* Wxb    = (const float*)d_in[6];
  const float* Whb    = (const float*)d_in[7];
  const float* bb_    = (const float*)d_in[8];
  const float* Wd     = (const float*)d_in[9];
  const float* bd     = (const float*)d_in[10];
  const float* trans  = (const float*)d_in[11];
  float* out = (float*)d_out;   // [logits 294912][seq_len 64][ll 64]

  char* ws = (char*)d_ws;
  ushort16* A    = (ushort16*)(ws + 0);           // 16 MB  bf16 emb rows
  ushort16* BT   = (ushort16*)(ws + 16777216);    //  1 MB  Wx^T bf16 (2048x256)
  uint32*   W2f  = (uint32*)  (ws + 17825792);    // 512 KB Wh_f half2 [128][1024]
  uint32*   W2b  = (uint32*)  (ws + 18350080);    // 512 KB
  ushort16* xgf  = (ushort16*)(ws + 18874368);    // 64 MB  bf16 [NT][1024]
  ushort16* xgb  = (ushort16*)(ws + 85983232);    // 64 MB
  float*    enc  = (float*)   (ws + 153092096);   // 64 MB  fp32 [NT][512]
  int*      slen = (int*)     (ws + 220200960);   // 256 B
  // h-exchange buffer: 16 WG x 2 parity x 16 batch x 64 pairs = 32768 u64 = 256 KB.
  // Reuses the A region (dead after k_gemm_xg); k_zero resets tags before k_lstm.
  uint64*   xh   = (uint64*)  (ws + 0);

  k_seqlen<<<BB, 64, 0, stream>>>(tokens, slen, out + NT * NL);
  k_embed <<<NT * 256 / 4 / 256, 256, 0, stream>>>(tokens, emb, A);
  k_wxprep<<<2048 * 256 / 256, 256, 0, stream>>>(Wxf, Wxb, BT);
  k_whprep<<<128 * 1024 / 256, 256, 0, stream>>>(Whf, W2f);
  k_whprep<<<128 * 1024 / 256, 256, 0, stream>>>(Whb, W2b);
  k_gemm_xg<<<dim3(NT / 64, 2048 / 64), 256, 0, stream>>>(A, BT, bf_, bb_, xgf, xgb);
  k_zero  <<<128, 256, 0, stream>>>(xh);   // 32768 u64 tags -> 0 (per replay)
  k_lstm  <<<16, 512, 0, stream>>>(xgf, xgb, W2f, W2b, xh, enc);
  k_dense <<<NT / 4, 256, 0, stream>>>(enc, Wd, bd, out);
  k_crf   <<<BB, 64, 0, stream>>>(out, labels, slen, trans, out + NT * NL + BB);
}

// Round 5
// 1302.050 us; speedup vs baseline: 1.5491x; 1.5491x over previous
//
#include <hip/hip_runtime.h>
#include <hip/hip_fp16.h>

// BiLSTM-CRF forward, MI355X. Round 8: k_lstm v8 = v6 structure + LDS-only
// raw barriers. v7 (MFMA batch) regressed -> reverted. Theory: v6's hidden
// ~2000 cyc/step was __syncthreads() draining vmcnt(0) (xg HBM prefetch,
// enc stores, LLC publishes) at 3 barriers/step. All barrier-ordered data is
// LDS-only, so use sched_barrier+s_waitcnt lgkmcnt(0)+s_barrier and let
// vmcnt free-run across barriers. Also: gate transcendentals (sig/tanh)
// moved from the 128-thread serial tail to the 512-thread gate-owner phase.

typedef unsigned int  uint32;
typedef unsigned short ushort16;
typedef unsigned long long uint64;
typedef __attribute__((ext_vector_type(8))) short  short8;   // 8 bf16 (4 VGPRs) — MFMA A/B frag
typedef __attribute__((ext_vector_type(4))) float  floatx4;  // MFMA C/D frag
typedef __attribute__((ext_vector_type(2))) _Float16 half2t;

#define BB 64
#define TT 512
#define NT (BB*TT)        // 32768 rows
#define G4 1024           // 4*H
#define NL 9

__device__ inline float bf2f(ushort16 u) {
  return __builtin_bit_cast(float, ((uint32)u) << 16);
}
__device__ inline ushort16 f2bf(float f) {  // RN-even bf16
  uint32 u = __builtin_bit_cast(uint32, f);
  u += 0x7fffu + ((u >> 16) & 1u);
  return (ushort16)(u >> 16);
}
__device__ inline float sigf(float x)  { return 1.0f / (1.0f + __expf(-x)); }
__device__ inline float tanhf_(float x){ return 1.0f - 2.0f / (1.0f + __expf(2.0f * x)); }

__device__ inline float fdot2_(uint32 w, half2t h, float acc) {
  return __builtin_amdgcn_fdot2(__builtin_bit_cast(half2t, w), h, acc, false);
}

// LDS-only workgroup barrier: orders LDS ops, lets vmcnt free-run.
// sched_barrier(0) fences both sides (rule #18: hipcc may hoist past asm).
__device__ inline void bar_lds() {
  __builtin_amdgcn_sched_barrier(0);
  asm volatile("s_waitcnt lgkmcnt(0)" ::: "memory");
  __builtin_amdgcn_s_barrier();
  __builtin_amdgcn_sched_barrier(0);
}

// ---------------- K1: seq_len ----------------
__global__ __launch_bounds__(64) void k_seqlen(const int* __restrict__ tokens,
                                               int* __restrict__ slen,
                                               float* __restrict__ out_sl) {
  const int b = blockIdx.x, lane = threadIdx.x;
  int cnt = 0;
  for (int t = lane; t < TT; t += 64) cnt += (tokens[b * TT + t] != 0) ? 1 : 0;
  #pragma unroll
  for (int off = 32; off >= 1; off >>= 1) cnt += __shfl_down(cnt, off, 64);
  if (lane == 0) { slen[b] = cnt; out_sl[b] = (float)cnt; }
}

// ---------------- K2a: embedding gather -> bf16 A matrix [NT][256] ----------------
__global__ __launch_bounds__(256) void k_embed(const int* __restrict__ tokens,
                                               const float* __restrict__ emb,
                                               ushort16* __restrict__ A) {
  const int f = blockIdx.x * 256 + threadIdx.x;  // float4 group, NT*256/4 total
  const int e = f * 4;
  const int row = e >> 8;
  const int col = e & 255;
  const int tok = tokens[row];
  const float4 v = *(const float4*)(emb + (size_t)tok * 256 + col);
  uint32 lo = (uint32)f2bf(v.x) | ((uint32)f2bf(v.y) << 16);
  uint32 hi = (uint32)f2bf(v.z) | ((uint32)f2bf(v.w) << 16);
  *(uint2*)(A + e) = make_uint2(lo, hi);
}

// ---------------- K2b: BT[c][k] = Wx_{f|b}[k][c] bf16, c in [0,2048) ----------------
__global__ __launch_bounds__(256) void k_wxprep(const float* __restrict__ Wxf,
                                                const float* __restrict__ Wxb,
                                                ushort16* __restrict__ BT) {
  const int id = blockIdx.x * 256 + threadIdx.x;   // 2048*256
  const int c = id >> 8, k = id & 255;
  const float v = (c < G4) ? Wxf[k * G4 + c] : Wxb[k * G4 + (c - G4)];
  BT[c * 256 + k] = f2bf(v);
}

// ---------------- K2c: Wh -> half2 pack, layout [k2][1024] ----------------
__global__ __launch_bounds__(256) void k_whprep(const float* __restrict__ Wh,
                                                uint32* __restrict__ W2) {
  const int id = blockIdx.x * 256 + threadIdx.x;   // 128*1024
  const int k2 = id >> 10, c = id & 1023;
  const float w0 = Wh[(2 * k2) * G4 + c];
  const float w1 = Wh[(2 * k2 + 1) * G4 + c];
  const ushort16 b0 = __builtin_bit_cast(ushort16, (_Float16)w0);
  const ushort16 b1 = __builtin_bit_cast(ushort16, (_Float16)w1);
  W2[id] = ((uint32)b1 << 16) | (uint32)b0;
}

// ---------------- K3: xg GEMM  [NT,256] @ [256,2048] -> bf16 xg_f | xg_b ----------------
__global__ __launch_bounds__(256) void k_gemm_xg(const ushort16* __restrict__ A,
                                                 const ushort16* __restrict__ BT,
                                                 const float* __restrict__ bias_f,
                                                 const float* __restrict__ bias_b,
                                                 ushort16* __restrict__ xgf,
                                                 ushort16* __restrict__ xgb) {
  __shared__ __align__(16) ushort16 As[64 * 36];
  __shared__ __align__(16) ushort16 Bs[64 * 36];
  const int m0 = blockIdx.x * 64;
  const int n0 = blockIdx.y * 64;
  const int tid = threadIdx.x;
  const int wave = tid >> 6, lane = tid & 63;
  const int lr = tid >> 2;            // staging row 0..63
  const int lc = (tid & 3) * 8;       // staging col {0,8,16,24}
  const int am = lane & 15, aq = lane >> 4;
  floatx4 acc[4];
  #pragma unroll
  for (int j = 0; j < 4; ++j) acc[j] = (floatx4){0.f, 0.f, 0.f, 0.f};

  for (int k0 = 0; k0 < 256; k0 += 32) {
    const uint4 va = *(const uint4*)(A  + ((m0 + lr) * 256 + k0 + lc));
    const uint4 vb = *(const uint4*)(BT + ((n0 + lr) * 256 + k0 + lc));
    *(uint2*)&As[lr * 36 + lc]     = make_uint2(va.x, va.y);
    *(uint2*)&As[lr * 36 + lc + 4] = make_uint2(va.z, va.w);
    *(uint2*)&Bs[lr * 36 + lc]     = make_uint2(vb.x, vb.y);
    *(uint2*)&Bs[lr * 36 + lc + 4] = make_uint2(vb.z, vb.w);
    __syncthreads();
    union { uint2 u[2]; short8 s; } fa, fb;
    fa.u[0] = *(const uint2*)&As[(wave * 16 + am) * 36 + aq * 8];
    fa.u[1] = *(const uint2*)&As[(wave * 16 + am) * 36 + aq * 8 + 4];
    #pragma unroll
    for (int j = 0; j < 4; ++j) {
      fb.u[0] = *(const uint2*)&Bs[(j * 16 + am) * 36 + aq * 8];
      fb.u[1] = *(const uint2*)&Bs[(j * 16 + am) * 36 + aq * 8 + 4];
      acc[j] = __builtin_amdgcn_mfma_f32_16x16x32_bf16(fa.s, fb.s, acc[j], 0, 0, 0);
    }
    __syncthreads();
  }
  // C/D layout (m89/m91-verified): col = lane&15, row = (lane>>4)*4 + reg
  const int orow = m0 + wave * 16 + aq * 4;
  #pragma unroll
  for (int j = 0; j < 4; ++j) {
    const int col = n0 + j * 16 + am;
    const float bv = (col < G4) ? bias_f[col] : bias_b[col - G4];
    #pragma unroll
    for (int r = 0; r < 4; ++r) {
      const float v = acc[j][r] + bv;
      const int row = orow + r;
      if (col < G4) xgf[row * G4 + col] = f2bf(v);
      else          xgb[row * G4 + (col - G4)] = f2bf(v);
    }
  }
}

// ---------------- K3b: zero the h-exchange tag buffer (per launch/replay) ----------------
__global__ __launch_bounds__(256) void k_zero(uint64* __restrict__ xh) {
  xh[blockIdx.x * 256 + threadIdx.x] = 0ull;
}

// ---------------- K4: LSTM recurrence v8 — 2 WGs/seq, LDS-only barriers ----
// Grid 256: bid -> dir=bid>>7, b=(bid>>1)&63, half=bid&1; partner = bid^1.
// 512 threads; thread tid: q=tid>>7 (gate), r=tid&127, col=q*256+half*128+r.
// wv[0..63]  = W2 rows (half*64 + i)      <- OWN-half k2 pairs (phase A)
// wv[64..127]= W2 rows ((1-half)*64 + i)  <- PEER-half k2 pairs (phase B)
// h2 LDS: slots [0,64) own pairs (local), [64,128) peer pairs (fetched).
// Barriers are LDS-only (bar_lds): vmcnt free-runs, so the per-step xg HBM
// prefetch / enc store / LLC publish never drain on the critical path.
// Gate transcendentals applied by the 512 gate-owner threads (q uniform);
// the 128-thread tail is c=F*c+I*G; h=O*tanh(c) — one transcendental chain.
__global__ __launch_bounds__(512, 2) void k_lstm(const ushort16* __restrict__ xgf,
                                                 const ushort16* __restrict__ xgb,
                                                 const uint32* __restrict__ Whf,
                                                 const uint32* __restrict__ Whb,
                                                 uint64* __restrict__ xh,
                                                 float* __restrict__ enc) {
  __shared__ __align__(16) uint32 h2[2][128];   // packed f16 h pairs, dbuf by parity
  __shared__ float gl[512];                     // transformed gate staging
  const int bid  = blockIdx.x;
  const int dir  = bid >> 7;
  const int b    = (bid >> 1) & 63;
  const int half = bid & 1;
  const int tid  = threadIdx.x;
  const int w = tid >> 6, l = tid & 63;
  const int q = tid >> 7, r = tid & 127;
  const int col = q * 256 + half * 128 + r;
  const ushort16* __restrict__ xg = dir ? xgb : xgf;
  const uint32* __restrict__ W2   = dir ? Whb : Whf;
  uint64* const xmine = xh + ((size_t)bid << 7);          // [2 par][64] u64
  const uint64* const xpeer = xh + ((size_t)(bid ^ 1) << 7);

  // Weight rows, permuted own-first. Runtime base only at LOAD time;
  // every later wv index is a literal (post-unroll).
  const int ownBase  = half * 64;
  const int peerBase = 64 - ownBase;
  uint32 wv[128];
  #pragma unroll
  for (int i = 0; i < 64; ++i) wv[i]      = W2[(ownBase  + i) * 1024 + col];
  #pragma unroll
  for (int i = 0; i < 64; ++i) wv[64 + i] = W2[(peerBase + i) * 1024 + col];
  #pragma unroll
  for (int i = 0; i < 128; ++i) asm volatile("" : "+v"(wv[i]));

  if (tid < 128) { h2[0][tid] = 0u; }  // h0 = 0 (own + peer slots)
  float c_state = 0.f;                 // live in tid<128
  __syncthreads();

  const int t0 = dir ? (TT - 1) : 0;
  ushort16 xA = xg[(size_t)(b * TT + t0) * G4 + col];

#define HC(u) __builtin_bit_cast(half2t, u)
#define GR4(B) { const uint4 hq = hb[B]; \
                 a0 = fdot2_(wv[(B)*4+0], HC(hq.x), a0); \
                 a1 = fdot2_(wv[(B)*4+1], HC(hq.y), a1); \
                 a2 = fdot2_(wv[(B)*4+2], HC(hq.z), a2); \
                 a3 = fdot2_(wv[(B)*4+3], HC(hq.w), a3); }

  for (int s = 0; s < TT; ++s) {
    const int par = s & 1;
    float a0 = bf2f(xA), a1 = 0.f, a2 = 0.f, a3 = 0.f;
    if (s + 1 < TT) {       // prefetch next step's x-gate (vmcnt never drained
      const int t1 = dir ? (TT - 2 - s) : (s + 1);   //  at barriers -> hidden)
      xA = xg[(size_t)(b * TT + t1) * G4 + col];
    }
    const uint4* hb = (const uint4*)h2[par];
    // ---- phase A: own half (slots 0..15, wv[0..63]) ----
    GR4(0)  GR4(1)  GR4(2)  GR4(3)  GR4(4)  GR4(5)  GR4(6)  GR4(7)
    GR4(8)  GR4(9)  GR4(10) GR4(11) GR4(12) GR4(13) GR4(14) GR4(15)
    // wave 0: poll peer (RT overlaps the dots above, which other waves run)
    if (w == 0 && s > 0) {
      const uint32 want = (uint32)s;
      uint64 v;
      for (;;) {
        v = __hip_atomic_load(xpeer + (par << 6) + l,
                              __ATOMIC_RELAXED, __HIP_MEMORY_SCOPE_AGENT);
        if (__all((uint32)(v >> 32) == want)) break;
        __builtin_amdgcn_s_sleep(1);
      }
      h2[par][64 + l] = (uint32)v;
    }
    bar_lds();         // peer half visible (LDS-only drain)
    // ---- phase B: peer half (slots 16..31, wv[64..127]) ----
    GR4(16) GR4(17) GR4(18) GR4(19) GR4(20) GR4(21) GR4(22) GR4(23)
    GR4(24) GR4(25) GR4(26) GR4(27) GR4(28) GR4(29) GR4(30) GR4(31)
    {
      float tv = (a0 + a1) + (a2 + a3);
      // apply gate nonlinearity here, in parallel across 512 threads
      // (q is wave-uniform: q=2 is the g-gate -> tanh, else sigmoid)
      tv = (q == 2) ? tanhf_(tv) : sigf(tv);
      gl[tid] = tv;
    }
    bar_lds();
    if (tid < 128) {   // tail: c = F*c + I*G; h = O*tanh(c)
      const float I = gl[tid];
      const float F = gl[128 + tid];
      const float G = gl[256 + tid];
      const float O = gl[384 + tid];
      c_state = F * c_state + I * G;
      const float h = O * tanhf_(c_state);
      // pack f16 pairs; even lanes own one dword (local pair index tid>>1)
      const int hv = (int)(uint32)__builtin_bit_cast(ushort16, (_Float16)h);
      const int ho = __shfl_xor(hv, 1, 64);
      if (!(tid & 1)) {
        const uint32 pk = ((uint32)hv & 0xffffu) | ((uint32)ho << 16);
        if (s + 1 < TT) {   // publish {tag=s+1, pair} for the peer WG — ASAP
          const uint64 pv = ((uint64)(uint32)(s + 1) << 32) | (uint64)pk;
          __hip_atomic_store(xmine + ((par ^ 1) << 6) + (tid >> 1), pv,
                             __ATOMIC_RELAXED, __HIP_MEMORY_SCOPE_AGENT);
        }
        h2[par ^ 1][tid >> 1] = pk;              // own slots [0,64)
      }
      const int t = dir ? (TT - 1 - s) : s;
      enc[(size_t)(b * TT + t) * 512 + dir * 256 + half * 128 + tid] = h;
    }
    bar_lds();
  }
#undef HC
#undef GR4
}

// ---------------- K5: logits = enc @ W_dense + b ----------------
__global__ __launch_bounds__(256) void k_dense(const float* __restrict__ enc,
                                               const float* __restrict__ Wd,
                                               const float* __restrict__ bd,
                                               float* __restrict__ logits) {
  __shared__ float Wl[512 * NL];
  __shared__ float bl[NL];
  const int tid = threadIdx.x;
  for (int i = tid; i < 512 * NL; i += 256) Wl[i] = Wd[i];
  if (tid < NL) bl[tid] = bd[tid];
  __syncthreads();
  const int wave = tid >> 6, lane = tid & 63;
  const int row = blockIdx.x * 4 + wave;
  const float* er = enc + (size_t)row * 512;
  float p[NL];
  #pragma unroll
  for (int c = 0; c < NL; ++c) p[c] = 0.f;
  #pragma unroll
  for (int u = 0; u < 8; ++u) {
    const int k = u * 64 + lane;
    const float v = er[k];
    const float* wr = &Wl[k * NL];
    #pragma unroll
    for (int c = 0; c < NL; ++c) p[c] += v * wr[c];
  }
  #pragma unroll
  for (int c = 0; c < NL; ++c) {
    #pragma unroll
    for (int off = 32; off >= 1; off >>= 1) p[c] += __shfl_down(p[c], off, 64);
  }
  if (lane == 0) {
    float* orow = logits + (size_t)row * NL;
    #pragma unroll
    for (int c = 0; c < NL; ++c) orow[c] = p[c] + bl[c];
  }
}

// ---------------- K6: CRF log-likelihood ----------------
__global__ __launch_bounds__(64) void k_crf(const float* __restrict__ logits,
                                            const int* __restrict__ labels,
                                            const int* __restrict__ slen,
                                            const float* __restrict__ trans,
                                            float* __restrict__ out_ll) {
  __shared__ float tr[NL * NL];
  __shared__ float alpha[NL];
  const int b = blockIdx.x;
  const int lane = threadIdx.x;
  for (int i = lane; i < NL * NL; i += 64) tr[i] = trans[i];
  __syncthreads();
  const int len = slen[b];
  const int* tg = labels + b * TT;
  const float* lg = logits + (size_t)b * TT * NL;
  float s = 0.f;
  for (int t = lane; t < TT; t += 64)
    if (t < len) s += lg[t * NL + tg[t]];
  for (int t = lane; t < TT - 1; t += 64)
    if (t + 1 < len) s += tr[tg[t] * NL + tg[t + 1]];
  #pragma unroll
  for (int off = 32; off >= 1; off >>= 1) s += __shfl_down(s, off, 64);
  if (lane < NL) alpha[lane] = lg[lane];
  __syncthreads();
  if (lane < NL) {
    const int j = lane;
    for (int t = 1; t < TT; ++t) {
      if (t < len) {
        float av[NL];
        float m = -1e30f;
        #pragma unroll
        for (int i = 0; i < NL; ++i) { av[i] = alpha[i] + tr[i * NL + j]; m = fmaxf(m, av[i]); }
        float ss = 0.f;
        #pragma unroll
        for (int i = 0; i < NL; ++i) ss += __expf(av[i] - m);
        const float nj = m + __logf(ss) + lg[t * NL + j];
        alpha[j] = nj;
      }
    }
  }
  __syncthreads();
  if (lane == 0) {
    float m = -1e30f;
    #pragma unroll
    for (int i = 0; i < NL; ++i) m = fmaxf(m, alpha[i]);
    float ss = 0.f;
    #pragma unroll
    for (int i = 0; i < NL; ++i) ss += __expf(alpha[i] - m);
    out_ll[b] = s - (m + __logf(ss));
  }
}

extern "C" void kernel_launch(void* const* d_in, const int* in_sizes, int n_in,
                              void* d_out, int out_size, void* d_ws, size_t ws_size,
                              hipStream_t stream) {
  (void)in_sizes; (void)n_in; (void)out_size; (void)ws_size;
  const int*   tokens = (const int*)d_in[0];
  const int*   labels = (const int*)d_in[1];
  const float* emb    = (const float*)d_in[2];
  const float* Wxf    = (const float*)d_in[3];
  const float* Whf    = (const float*)d_in[4];
  const float* bf_    = (const float*)d_in[5];
  const float* Wxb    = (const float*)d_in[6];
  const float* Whb    = (const float*)d_in[7];
  const float* bb_    = (const float*)d_in[8];
  const float* Wd     = (const float*)d_in[9];
  const float* bd     = (const float*)d_in[10];
  const float* trans  = (const float*)d_in[11];
  float* out = (float*)d_out;   // [logits 294912][seq_len 64][ll 64]

  char* ws = (char*)d_ws;
  ushort16* A    = (ushort16*)(ws + 0);           // 16 MB  bf16 emb rows
  ushort16* BT   = (ushort16*)(ws + 16777216);    //  1 MB  Wx^T bf16 (2048x256)
  uint32*   W2f  = (uint32*)  (ws + 17825792);    // 512 KB Wh_f half2 [128][1024]
  uint32*   W2b  = (uint32*)  (ws + 18350080);    // 512 KB
  ushort16* xgf  = (ushort16*)(ws + 18874368);    // 64 MB  bf16 [NT][1024]
  ushort16* xgb  = (ushort16*)(ws + 85983232);    // 64 MB
  float*    enc  = (float*)   (ws + 153092096);   // 64 MB  fp32 [NT][512]
  int*      slen = (int*)     (ws + 220200960);   // 256 B
  // h-exchange buffer: 256 WG x 2 parity x 64 u64 = 256 KB.
  // Reuses the A region (dead after k_gemm_xg); k_zero resets tags before k_lstm.
  uint64*   xh   = (uint64*)  (ws + 0);

  k_seqlen<<<BB, 64, 0, stream>>>(tokens, slen, out + NT * NL);
  k_embed <<<NT * 256 / 4 / 256, 256, 0, stream>>>(tokens, emb, A);
  k_wxprep<<<2048 * 256 / 256, 256, 0, stream>>>(Wxf, Wxb, BT);
  k_whprep<<<128 * 1024 / 256, 256, 0, stream>>>(Whf, W2f);
  k_whprep<<<128 * 1024 / 256, 256, 0, stream>>>(Whb, W2b);
  k_gemm_xg<<<dim3(NT / 64, 2048 / 64), 256, 0, stream>>>(A, BT, bf_, bb_, xgf, xgb);
  k_zero  <<<128, 256, 0, stream>>>(xh);   // 32768 u64 tags -> 0 (per replay)
  k_lstm  <<<256, 512, 0, stream>>>(xgf, xgb, W2f, W2b, xh, enc);
  k_dense <<<NT / 4, 256, 0, stream>>>(enc, Wd, bd, out);
  k_crf   <<<BB, 64, 0, stream>>>(out, labels, slen, trans, out + NT * NL + BB);
}